// Round 1
// baseline (301.251 us; speedup 1.0000x reference)
//
#include <hip/hip_runtime.h>
#include <hip/hip_bf16.h>
#include <stdint.h>

typedef __bf16 bf16_t;
typedef __bf16 bf16x4 __attribute__((ext_vector_type(4)));
typedef __bf16 bf16x8 __attribute__((ext_vector_type(8)));
typedef float  f32x4  __attribute__((ext_vector_type(4)));

#define AS1 __attribute__((address_space(1)))
#define AS3 __attribute__((address_space(3)))

// async global->LDS, 16B per lane; lds dest = wave-uniform base + lane*16
__device__ __forceinline__ void gld_lds16(const void* gp, void* lp) {
    __builtin_amdgcn_global_load_lds((const AS1 unsigned int*)gp,
                                     (AS3 unsigned int*)lp, 16, 0, 0);
}

__device__ __forceinline__ bf16_t bhi(float v) { return (bf16_t)v; }
__device__ __forceinline__ bf16_t blo(float v) {
    return (bf16_t)(v - (float)((bf16_t)v));
}

// ---------------------------------------------------------------------------
// Kernel 1: W fp32 -> bf16
// ---------------------------------------------------------------------------
__global__ __launch_bounds__(256) void wconv_kernel(const float* __restrict__ W,
                                                    bf16_t* __restrict__ Wb) {
    const int i = (blockIdx.x * 256 + threadIdx.x) * 4;
    const float4 f = *(const float4*)&W[i];
    bf16x4 v = { (bf16_t)f.x, (bf16_t)f.y, (bf16_t)f.z, (bf16_t)f.w };
    *(bf16x4*)&Wb[i] = v;
}

// ---------------------------------------------------------------------------
// Kernel 2: attention per (b,h).  L=64, E=128.  fp32 in, bf16 X out.
//
// Restructured (vs 298us version) to kill latency/barrier serialization:
//  - Q is WAVE-PRIVATE (score A-operand rows 16w..16w+15): each lane loads its
//    exact MFMA A-fragment (row 16w+row16, chunks 32kc+8quad) from global into
//    registers, hi+lo bf16.  No Q LDS, no Q staging barriers.
//  - K lo and hi staged into two separate LDS slots up-front -> the 3 Gray
//    passes (Qh*Kl, Qh*Kh, Ql*Kh) run back-to-back with NO barriers between.
//  - V loaded lane-major (s=lane, cols 32w..+31) -> transposed scalar LDS
//    writes are bank-conflict-free within every 16-lane group.
//  - Softmax fully in-register: lane holds S[16w+4q+rr][16ni+row16]; row
//    reduce = 3 VALU (ni) + shfl_xor 1/2/4/8 (row16).  No fp32 S spill.
//  - P (unnormalized bf16) and O buffers are wave-local, placed in the dead
//    KL/KH slots; only lgkmcnt waits, no barriers.  1/sum folded after PV.
//  => TWO __syncthreads total.  LDS 48 KiB -> 3 blocks/CU.
//  All LDS layouts use 16B-chunk XOR swizzles (chunk ^ f(row)) chosen so each
//  16-lane phase hits distinct banks for both writes and ds_read_b128.
// ---------------------------------------------------------------------------
__global__ __launch_bounds__(256, 3) void attn_kernel(const float* __restrict__ Q,
                                                      const float* __restrict__ K,
                                                      const float* __restrict__ V,
                                                      bf16_t* __restrict__ X) {
    // LDS plan (bytes):
    //   KL : [0, 16384)      64x128 bf16 swz   (K lo)   -> Ps overlay after scores
    //   KH : [16384, 32768)  64x128 bf16 swz   (K hi)   -> Ob overlay after scores
    //   Vt : [32768, 49152)  128x64 bf16 swz   (V^T)    live whole kernel
    __shared__ __align__(16) char smem[49152];
    bf16_t* KL = (bf16_t*)smem;
    bf16_t* KH = (bf16_t*)(smem + 16384);
    bf16_t* Vt = (bf16_t*)(smem + 32768);
    bf16_t* Ps = (bf16_t*)smem;             // 64x64 swz, wave-local rows
    bf16_t* Ob = (bf16_t*)(smem + 16384);   // 64x128 swz, wave-local rows

    const int bh    = blockIdx.x;          // b*16 + h
    const int b     = bh >> 4;
    const int h     = bh & 15;
    const int t     = threadIdx.x;
    const int w     = t >> 6;              // wave 0..3
    const int lane  = t & 63;
    const int row16 = lane & 15;
    const int quad  = lane >> 4;

    const float* Qg = Q + (size_t)bh * 8192;
    const float* Kg = K + (size_t)bh * 8192;
    const float* Vg = V + (size_t)bh * 8192;

    // ---- Q: per-lane direct load of this lane's A-fragments (hi+lo) ----
    bf16x8 qh8[4], ql8[4];
    {
        const float* qrow = Qg + (size_t)(16 * w + row16) * 128 + 8 * quad;
#pragma unroll
        for (int kc = 0; kc < 4; ++kc) {
            const float4 f0 = *(const float4*)&qrow[32 * kc];
            const float4 f1 = *(const float4*)&qrow[32 * kc + 4];
            const float f[8] = { f0.x, f0.y, f0.z, f0.w, f1.x, f1.y, f1.z, f1.w };
            bf16x8 hi, lo;
#pragma unroll
            for (int j = 0; j < 8; ++j) {
                const bf16_t hv = (bf16_t)f[j];
                hi[j] = hv;
                lo[j] = (bf16_t)(f[j] - (float)hv);
            }
            qh8[kc] = hi;
            ql8[kc] = lo;
        }
    }

    // ---- K: stage lo->KL, hi->KH (shared), swizzled chunk = c8 ^ (row&7) ----
    {
        const int r   = t >> 2;
        const int c0  = (t & 3) * 32;
        const int rsw = r & 7;
#pragma unroll
        for (int j = 0; j < 8; ++j) {
            const int c = c0 + 4 * j;
            const float4 f = *(const float4*)&Kg[r * 128 + c];
            bf16x4 hi = { bhi(f.x), bhi(f.y), bhi(f.z), bhi(f.w) };
            bf16x4 lo = { blo(f.x), blo(f.y), blo(f.z), blo(f.w) };
            const int addr = r * 128 + ((((c >> 3) ^ rsw)) << 3) + (c & 7);
            *(bf16x4*)&KH[addr] = hi;
            *(bf16x4*)&KL[addr] = lo;
        }
    }

    // ---- V: lane-major load (s=lane, cols 32w..+31) -> Vt[d][s] swizzled ----
    {
        const int s = lane;
#pragma unroll
        for (int j = 0; j < 8; ++j) {
            const int d0 = 32 * w + 4 * j;
            const float4 f = *(const float4*)&Vg[(size_t)s * 128 + d0];
            const float ff[4] = { f.x, f.y, f.z, f.w };
#pragma unroll
            for (int i = 0; i < 4; ++i) {
                const int d = d0 + i;
                Vt[d * 64 + ((((s >> 3) ^ (d & 7))) << 3) + (s & 7)] = (bf16_t)ff[i];
            }
        }
    }

    __syncthreads();   // B1: K/V staged

    // ---- scores: 3 Gray passes, no intervening barriers ----
    f32x4 accS[4];
#pragma unroll
    for (int ni = 0; ni < 4; ++ni) accS[ni] = (f32x4){0.f, 0.f, 0.f, 0.f};
    const int bsw = row16 & 7;

#define SPASS(AREG, BS)                                                        \
    {                                                                          \
        _Pragma("unroll")                                                      \
        for (int kc = 0; kc < 4; ++kc) {                                       \
            const bf16x8 a = AREG[kc];                                         \
            _Pragma("unroll")                                                  \
            for (int ni = 0; ni < 4; ++ni) {                                   \
                const bf16x8 bb = *(const bf16x8*)&BS[(16 * ni + row16) * 128  \
                                       + ((((4 * kc + quad) ^ bsw)) << 3)];    \
                accS[ni] = __builtin_amdgcn_mfma_f32_16x16x32_bf16(a, bb, accS[ni], 0, 0, 0); \
            }                                                                  \
        }                                                                      \
    }

    __builtin_amdgcn_s_setprio(1);
    SPASS(qh8, KL)      // Qh * Kl
    SPASS(qh8, KH)      // Qh * Kh
    SPASS(ql8, KH)      // Ql * Kh   ((l,l) term ~2^-18 relative — negligible)
    __builtin_amdgcn_s_setprio(0);

    // ---- softmax fully in-register ----
    // lane holds S[l=16w+4q+rr][s=16ni+row16]; reduce over ni in-lane, over
    // row16 via shfl_xor (lanes of a quad share rows).
    float e[4][4];      // e[ni][rr]
    float inv_[4];
    const float cs = 0.1f * 1.44269504088896f;   // scale * log2(e)
#pragma unroll
    for (int rr = 0; rr < 4; ++rr) {
        float m = fmaxf(fmaxf(accS[0][rr], accS[1][rr]),
                        fmaxf(accS[2][rr], accS[3][rr]));
        m = fmaxf(m, __shfl_xor(m, 1));
        m = fmaxf(m, __shfl_xor(m, 2));
        m = fmaxf(m, __shfl_xor(m, 4));
        m = fmaxf(m, __shfl_xor(m, 8));
        float s0 = 0.f;
#pragma unroll
        for (int ni = 0; ni < 4; ++ni) {
            const float ev = exp2f((accS[ni][rr] - m) * cs);
            e[ni][rr] = ev;
            s0 += ev;
        }
        s0 += __shfl_xor(s0, 1);
        s0 += __shfl_xor(s0, 2);
        s0 += __shfl_xor(s0, 4);
        s0 += __shfl_xor(s0, 8);
        inv_[rr] = 1.0f / s0;    // folded in after PV
    }

    __syncthreads();   // B2: all score LDS reads done -> KL/KH reusable

    // ---- P (unnormalized, bf16) -> Ps (KL region, wave-local rows) ----
#pragma unroll
    for (int rr = 0; rr < 4; ++rr) {
        const int l   = 16 * w + 4 * quad + rr;
        const int lsw = l & 7;
#pragma unroll
        for (int ni = 0; ni < 4; ++ni) {
            const int s = 16 * ni + row16;
            Ps[l * 64 + ((((s >> 3) ^ lsw)) << 3) + (s & 7)] = (bf16_t)e[ni][rr];
        }
    }
    asm volatile("s_waitcnt lgkmcnt(0)" ::: "memory");
    __builtin_amdgcn_sched_barrier(0);

    // ---- O[l,d] = sum_s P[l,s] V[s,d] ----
    f32x4 accO[8];
#pragma unroll
    for (int ni = 0; ni < 8; ++ni) accO[ni] = (f32x4){0.f, 0.f, 0.f, 0.f};
    __builtin_amdgcn_s_setprio(1);
#pragma unroll
    for (int kb = 0; kb < 2; ++kb) {
        const bf16x8 a = *(const bf16x8*)&Ps[(16 * w + row16) * 64
                               + ((((4 * kb + quad) ^ bsw)) << 3)];
#pragma unroll
        for (int ni = 0; ni < 8; ++ni) {
            const bf16x8 bb = *(const bf16x8*)&Vt[(16 * ni + row16) * 64
                                   + ((((4 * kb + quad) ^ bsw)) << 3)];
            accO[ni] = __builtin_amdgcn_mfma_f32_16x16x32_bf16(a, bb, accO[ni], 0, 0, 0);
        }
    }
    __builtin_amdgcn_s_setprio(0);

    // ---- O -> Ob (KH region, wave-local rows), scale by 1/sum ----
#pragma unroll
    for (int ni = 0; ni < 8; ++ni)
#pragma unroll
        for (int rr = 0; rr < 4; ++rr) {
            const int l = 16 * w + 4 * quad + rr;   // l&3 == rr
            const int d = 16 * ni + row16;
            Ob[l * 128 + ((((d >> 3) ^ (5 * rr))) << 3) + (d & 7)] =
                (bf16_t)(accO[ni][rr] * inv_[rr]);
        }
    asm volatile("s_waitcnt lgkmcnt(0)" ::: "memory");
    __builtin_amdgcn_sched_barrier(0);

    // ---- coalesced store of this wave's 16 rows ----
    {
        const int lr = 16 * w + (lane >> 2);
        bf16_t* Xrow = X + (size_t)b * 64 * 2048 + h * 128 + (size_t)lr * 2048;
#pragma unroll
        for (int jj = 0; jj < 4; ++jj) {
            const int c8 = (lane & 3) + 4 * jj;
            const bf16x8 v = *(const bf16x8*)&Ob[lr * 128 + ((c8 ^ (5 * (lr & 3))) << 3)];
            *(bf16x8*)&Xrow[8 * c8] = v;
        }
    }
}

// ---------------------------------------------------------------------------
// Kernel 3: out[m,n] = sum_k X[m,k] Wb[n,k] + bias[n]  (M=8192,N=2048,K=2048)
// 128x128 tile, BK=64, 256 thr, 4 blocks/CU, global_load_lds width 16.
// LDS tile [128 rows][8 chunks of 16B] with XOR swizzle p = q ^ (row&7):
// fragment reads hit all 32 banks evenly (conflict-free).
// Grid x = M-tiles so each XCD's X slice (4 MiB) stays L2-resident.
// ---------------------------------------------------------------------------
__global__ __launch_bounds__(256, 4) void gemm_kernel(const bf16_t* __restrict__ X,
                                                      const bf16_t* __restrict__ Wb,
                                                      const float* __restrict__ bias,
                                                      float* __restrict__ out) {
    __shared__ bf16_t As[128 * 64];   // 16 KiB
    __shared__ bf16_t Bs[128 * 64];   // 16 KiB

    const int t    = threadIdx.x;
    const int w    = t >> 6;
    const int lane = t & 63;
    const int row16 = lane & 15;
    const int quad  = lane >> 4;
    const int m0 = blockIdx.x * 128;   // x = M (XCD locality for X)
    const int n0 = blockIdx.y * 128;
    const int wm = w >> 1;             // 2x2 wave grid, each wave 64x64
    const int wn = w & 1;

    // staging: wave w stages rows [32w,32w+32) of each tile, 4 insts of 8 rows.
    // lane -> (row8 = lane>>3, q = lane&7); global col swizzled: 8*(q ^ row8)
    const int row8 = lane >> 3;
    const int scol = 8 * ((lane & 7) ^ (row8 & 7));
    const bf16_t* gA = X  + (size_t)(m0 + 32 * w + row8) * 2048 + scol;
    const bf16_t* gB = Wb + (size_t)(n0 + 32 * w + row8) * 2048 + scol;
    bf16_t* lA = &As[(32 * w) * 64];
    bf16_t* lB = &Bs[(32 * w) * 64];

    // fragment read offsets (elements), swizzled: row*64 + 8*((4*kk+quad)^(row&7))
    const int sw = row16 & 7;
    int aoff[4][2], boff[4][2];
#pragma unroll
    for (int mi = 0; mi < 4; ++mi)
#pragma unroll
        for (int kk = 0; kk < 2; ++kk) {
            const int ar = 64 * wm + 16 * mi + row16;
            const int br = 64 * wn + 16 * mi + row16;
            aoff[mi][kk] = ar * 64 + 8 * ((4 * kk + quad) ^ sw);
            boff[mi][kk] = br * 64 + 8 * ((4 * kk + quad) ^ sw);
        }

    f32x4 acc[4][4];
#pragma unroll
    for (int mi = 0; mi < 4; ++mi)
#pragma unroll
        for (int ni = 0; ni < 4; ++ni) acc[mi][ni] = (f32x4){0.f, 0.f, 0.f, 0.f};

    for (int kb = 0; kb < 32; ++kb) {
        const int k0 = kb * 64;
        __syncthreads();                       // previous compute done before overwrite
#pragma unroll
        for (int i = 0; i < 4; ++i) {
            gld_lds16(gA + (size_t)(8 * i) * 2048 + k0, lA + (8 * i) * 64);
            gld_lds16(gB + (size_t)(8 * i) * 2048 + k0, lB + (8 * i) * 64);
        }
        __syncthreads();                       // staged (compiler drains vmcnt)

#pragma unroll
        for (int kk = 0; kk < 2; ++kk) {
            bf16x8 a[4], bb[4];
#pragma unroll
            for (int mi = 0; mi < 4; ++mi) a[mi]  = *(const bf16x8*)&As[aoff[mi][kk]];
#pragma unroll
            for (int ni = 0; ni < 4; ++ni) bb[ni] = *(const bf16x8*)&Bs[boff[ni][kk]];
#pragma unroll
            for (int mi = 0; mi < 4; ++mi)
#pragma unroll
                for (int ni = 0; ni < 4; ++ni)
                    acc[mi][ni] = __builtin_amdgcn_mfma_f32_16x16x32_bf16(a[mi], bb[ni], acc[mi][ni], 0, 0, 0);
        }
    }

    // epilogue: add bias, store FP32
    const int nb = n0 + 64 * wn;
    float br[4];
#pragma unroll
    for (int ni = 0; ni < 4; ++ni) br[ni] = bias[nb + 16 * ni + row16];
#pragma unroll
    for (int mi = 0; mi < 4; ++mi)
#pragma unroll
        for (int ni = 0; ni < 4; ++ni)
#pragma unroll
            for (int rr = 0; rr < 4; ++rr) {
                const int m = m0 + 64 * wm + 16 * mi + 4 * quad + rr;
                const int n = nb + 16 * ni + row16;
                out[(size_t)m * 2048 + n] = acc[mi][ni][rr] + br[ni];
            }
}

// ---------------------------------------------------------------------------
extern "C" void kernel_launch(void* const* d_in, const int* in_sizes, int n_in,
                              void* d_out, int out_size, void* d_ws, size_t ws_size,
                              hipStream_t stream) {
    const float* Q    = (const float*)d_in[0];
    const float* K    = (const float*)d_in[1];
    const float* V    = (const float*)d_in[2];
    const float* W    = (const float*)d_in[3];
    const float* bias = (const float*)d_in[4];

    bf16_t* Xws = (bf16_t*)d_ws;                                    // 32 MiB
    bf16_t* Wb  = (bf16_t*)((char*)d_ws + (size_t)8192 * 2048 * 2); // 8 MiB
    float*  out = (float*)d_out;

    wconv_kernel<<<4096, 256, 0, stream>>>(W, Wb);
    attn_kernel<<<2048, 256, 0, stream>>>(Q, K, V, Xws);
    gemm_kernel<<<dim3(64, 16), 256, 0, stream>>>(Xws, Wb, bias, out);
}